// Round 6
// baseline (216.243 us; speedup 1.0000x reference)
//
#include <hip/hip_runtime.h>

// ---------------------------------------------------------------------------
// MultiHeadAttention (B=2,S=2048,H=16,DH=64,D=1024), fp32 in/out, fp16 MFMA.
// Pipeline: prep (xcvt + wtrans) -> QKV gemm (Q prescaled, V transposed)
//           -> flash attn v4 -> O gemm.
// attn v4: one 64-q tile per block, grid 1024 (4 blocks/CU, LDS 36 KB);
//   O^T = V*P^T with in-register C->B-frag transform (shfl; no Ps LDS);
//   LDS-dbuf + reg prefetch = 1 barrier/tile; fixed-shift softmax;
//   XCD-pinned bh + big/small qt interleave for CU balance.
// v5 fix: diagonal mask uses the lane's q WITHIN THE BLOCK (wv*16+r), not r.
// MFMA 16x16x32 f16 layouts (verified, rounds 1-3 passed):
//   A: m=lane&15, k=quad*8+j   B: n=lane&15, k=quad*8+j
//   C/D: col(n)=lane&15, row(m)=quad*4+reg
// ---------------------------------------------------------------------------

typedef _Float16 f16x8 __attribute__((ext_vector_type(8)));
typedef float f32x4 __attribute__((ext_vector_type(4)));

#define GLD_LDS16(g, l)                                                        \
  __builtin_amdgcn_global_load_lds(                                            \
      (__attribute__((address_space(1))) const unsigned int*)(g),              \
      (__attribute__((address_space(3))) unsigned int*)(l), 16, 0, 0)

static constexpr int Sdim = 2048;
static constexpr int Ddim = 1024;
static constexpr int NH = 16;
static constexpr int DH = 64;
static constexpr int Mrows = 4096;  // B*S

// Q prescale: 1/sqrt(64) * log2(e), so P = exp2(S' - SHIFT) natively.
static constexpr float QSCALE = 0.125f * 1.44269504f;
static constexpr float SHIFT = 4.0f;

// ------------------- prep: X fp32->fp16  +  W [K,N]->fp16 [N,K] ------------
struct WtArgs {
  const float *s0, *s1, *s2, *s3;
  _Float16 *d0, *d1, *d2, *d3;
};

__global__ __launch_bounds__(256) void prep(const float* __restrict__ X,
                                            _Float16* __restrict__ Y, WtArgs a) {
  __shared__ _Float16 L[64 * 72];
  const int bid = blockIdx.x, t = threadIdx.x;
  if (bid < 2048) {  // xcvt: 4096x1024 fp32 -> fp16
    size_t i = ((size_t)bid * 256 + t) * 8;
    float4 f0 = *(const float4*)(X + i);
    float4 f1 = *(const float4*)(X + i + 4);
    alignas(16) _Float16 h[8] = {(_Float16)f0.x, (_Float16)f0.y, (_Float16)f0.z,
                                 (_Float16)f0.w, (_Float16)f1.x, (_Float16)f1.y,
                                 (_Float16)f1.z, (_Float16)f1.w};
    *(uint4*)(Y + i) = *(const uint4*)h;
    return;
  }
  const int w = bid - 2048, z = w >> 8, rem = w & 255;
  const float* src = z == 0 ? a.s0 : z == 1 ? a.s1 : z == 2 ? a.s2 : a.s3;
  _Float16* dst = z == 0 ? a.d0 : z == 1 ? a.d1 : z == 2 ? a.d2 : a.d3;
  const int k0 = (rem & 15) * 64, n0 = (rem >> 4) * 64;
#pragma unroll
  for (int i = 0; i < 4; ++i) {
    int c = i * 256 + t;  // 1024 chunks of 4 floats
    int row = c >> 4, cc = c & 15;
    float4 f = *(const float4*)&src[(size_t)(k0 + row) * Ddim + n0 + cc * 4];
    L[(cc * 4 + 0) * 72 + row] = (_Float16)f.x;
    L[(cc * 4 + 1) * 72 + row] = (_Float16)f.y;
    L[(cc * 4 + 2) * 72 + row] = (_Float16)f.z;
    L[(cc * 4 + 3) * 72 + row] = (_Float16)f.w;
  }
  __syncthreads();
#pragma unroll
  for (int i = 0; i < 2; ++i) {
    int c = i * 256 + t;  // 512 chunks of 8 halves
    int n = c >> 3, cc = c & 7;
    *(uint4*)&dst[(size_t)(n0 + n) * Ddim + k0 + cc * 8] =
        *(const uint4*)&L[n * 72 + cc * 8];
  }
}

// --------------------------- 128x128 GEMM ----------------------------------
// A [M,1024] fp16, Bt [N=1024,K=1024] fp16.
// MODE 0: +bias -> fp16; z==0 (Q): prescale by QSCALE -> [B,H,S,64]
//                        z==1 (K): -> [B,H,S,64]
//                        z==2 (V): -> transposed [B,H,64,S]
// MODE 1: +bias -> fp32 [M,1024] row-major (d_out).
struct GemmArgs {
  const _Float16* A;
  const _Float16 *Bt0, *Bt1, *Bt2;
  const float *b0, *b1, *b2;
  void *o0, *o1, *o2;
};

template <int MODE>
__global__ __launch_bounds__(256) void gemm128(GemmArgs g) {
  constexpr int K = 1024;
  __shared__ _Float16 As[128 * 32];
  __shared__ _Float16 Bs[128 * 32];
  const int z = blockIdx.z;
  const _Float16* A = g.A;
  const _Float16* Bt = z == 0 ? g.Bt0 : z == 1 ? g.Bt1 : g.Bt2;
  const float* bias = z == 0 ? g.b0 : z == 1 ? g.b1 : g.b2;
  void* out = z == 0 ? g.o0 : z == 1 ? g.o1 : g.o2;
  const int m0 = blockIdx.x * 128, n0 = blockIdx.y * 128;
  const int t = threadIdx.x, lane = t & 63, wv = t >> 6;
  const int wm = wv >> 1, wn = wv & 1, quad = lane >> 4, r = lane & 15;

  // staging chunks: 512 x 16B per tile; chunk c -> row c>>2, k-off (c&3)*8
  const int c0 = wv * 64 + lane, c1 = c0 + 256;
  const _Float16* ga0 = A + (size_t)(m0 + (c0 >> 2)) * K + (c0 & 3) * 8;
  const _Float16* ga1 = A + (size_t)(m0 + (c1 >> 2)) * K + (c1 & 3) * 8;
  const _Float16* gb0 = Bt + (size_t)(n0 + (c0 >> 2)) * K + (c0 & 3) * 8;
  const _Float16* gb1 = Bt + (size_t)(n0 + (c1 >> 2)) * K + (c1 & 3) * 8;
  char* lA0 = (char*)As + (wv * 64) * 16;
  char* lA1 = (char*)As + (256 + wv * 64) * 16;
  char* lB0 = (char*)Bs + (wv * 64) * 16;
  char* lB1 = (char*)Bs + (256 + wv * 64) * 16;

  f32x4 acc[4][4] = {};
  for (int kt = 0; kt < K; kt += 32) {
    GLD_LDS16(ga0 + kt, lA0);
    GLD_LDS16(ga1 + kt, lA1);
    GLD_LDS16(gb0 + kt, lB0);
    GLD_LDS16(gb1 + kt, lB1);
    __syncthreads();
    f16x8 af[4], bf[4];
#pragma unroll
    for (int mi = 0; mi < 4; ++mi)
      af[mi] = *(const f16x8*)&As[(wm * 64 + mi * 16 + r) * 32 + quad * 8];
#pragma unroll
    for (int ni = 0; ni < 4; ++ni)
      bf[ni] = *(const f16x8*)&Bs[(wn * 64 + ni * 16 + r) * 32 + quad * 8];
#pragma unroll
    for (int mi = 0; mi < 4; ++mi)
#pragma unroll
      for (int ni = 0; ni < 4; ++ni)
        acc[mi][ni] = __builtin_amdgcn_mfma_f32_16x16x32_f16(af[mi], bf[ni],
                                                             acc[mi][ni], 0, 0, 0);
    __syncthreads();
  }

  const float scale = (MODE == 0 && z == 0) ? QSCALE : 1.0f;
  float bv[4];
#pragma unroll
  for (int ni = 0; ni < 4; ++ni) bv[ni] = bias[n0 + wn * 64 + ni * 16 + r];
#pragma unroll
  for (int mi = 0; mi < 4; ++mi) {
#pragma unroll
    for (int ni = 0; ni < 4; ++ni) {
      const int n = n0 + wn * 64 + ni * 16 + r;
      if (MODE == 0 && z == 2) {
        // V: write transposed [B,H,64,S]; 4 regs are s-contiguous -> 8B store
        alignas(8) _Float16 h4[4];
#pragma unroll
        for (int reg = 0; reg < 4; ++reg)
          h4[reg] = (_Float16)(acc[mi][ni][reg] + bv[ni]);
        const int m = m0 + wm * 64 + mi * 16 + quad * 4;
        const int b = m >> 11, s = m & 2047, h = n >> 6, dh = n & 63;
        *(uint2*)&((_Float16*)out)[((size_t)(b * NH + h) * DH + dh) * Sdim + s] =
            *(const uint2*)h4;
      } else {
#pragma unroll
        for (int reg = 0; reg < 4; ++reg) {
          const int m = m0 + wm * 64 + mi * 16 + quad * 4 + reg;
          const float v = (acc[mi][ni][reg] + bv[ni]) * scale;
          if (MODE == 0) {
            const int b = m >> 11, s = m & 2047, h = n >> 6, dh = n & 63;
            ((_Float16*)out)[(((size_t)(b * NH + h) * Sdim + s) << 6) + dh] =
                (_Float16)v;
          } else {
            ((float*)out)[(size_t)m * Ddim + n] = v;
          }
        }
      }
    }
  }
}

// ------------------------- flash attention v4 ------------------------------
// grid 1024, 256 thr. One 64-q tile per block. id -> (xcd=id&7, b2, qi):
// bh = xcd + 8*b2 (bh pinned to one XCD); qt = big/small interleave so any
// 4-block CU packing (consecutive or strided) sums to ~66 tile-units.
__global__ __launch_bounds__(256) void attn(const _Float16* __restrict__ Q,
                                            const _Float16* __restrict__ Kk,
                                            const _Float16* __restrict__ Vt,
                                            _Float16* __restrict__ ctx) {
  constexpr int LDK = 72;
  __shared__ _Float16 Ks[2][64 * LDK], Vs[2][64 * LDK];
  const int id = blockIdx.x, xcd = id & 7, k = id >> 3;
  const int b2 = (k >> 5) & 3, qi = k & 31;
  const int gg = ((qi >> 1) + 9 * b2) & 15;
  const int qt = (qi & 1) ? (31 - gg) : gg;
  const int bh = xcd + 8 * b2;
  const int t = threadIdx.x, lane = t & 63, wv = t >> 6;
  const int quad = lane >> 4, r = lane & 15;
  const _Float16* Kg = Kk + (size_t)bh * Sdim * DH;       // [S, 64]
  const _Float16* Vg = Vt + (size_t)bh * DH * Sdim;       // [64, S]
  const int q0 = qt * 64;

  // Q B-frags for this wave's 16 q rows (q = wv*16 + r)
  const _Float16* Qrow = Q + ((size_t)bh * Sdim + q0 + wv * 16 + r) * DH;
  const f16x8 bq0 = *(const f16x8*)(Qrow + quad * 8);
  const f16x8 bq1 = *(const f16x8*)(Qrow + 32 + quad * 8);

  // staging: 512 16B-chunks per 64x64 tile; thread covers rows sr0, sr0+32
  const int sr0 = t >> 3, sr1 = sr0 + 32, sc0 = (t & 7) * 8;
  const _Float16* pk0 = Kg + sr0 * DH + sc0;
  const _Float16* pk1 = Kg + sr1 * DH + sc0;
  const _Float16* pv0 = Vg + (size_t)sr0 * Sdim + sc0;
  const _Float16* pv1 = Vg + (size_t)sr1 * Sdim + sc0;

  // shfl source lanes for the P^T(C-layout) -> B-frag transform
  const int sl = ((quad & 1) << 5) + r, sh = sl + 16;

  float l_i = 0.f;
  f32x4 oaccT[4] = {};  // O^T: tile ni -> dh=16ni+4quad+reg, q=r

  const int ntiles = qt + 1;
  uint4 ka = *(const uint4*)pk0, kb = *(const uint4*)pk1;
  uint4 va = *(const uint4*)pv0, vb = *(const uint4*)pv1;

  for (int it = 0; it < ntiles; ++it) {
    const int cur = it & 1;
    *(uint4*)&Ks[cur][sr0 * LDK + sc0] = ka;
    *(uint4*)&Ks[cur][sr1 * LDK + sc0] = kb;
    *(uint4*)&Vs[cur][sr0 * LDK + sc0] = va;
    *(uint4*)&Vs[cur][sr1 * LDK + sc0] = vb;
    __syncthreads();
    if (it + 1 < ntiles) {  // prefetch next tile (in flight during compute)
      pk0 += 64 * DH; pk1 += 64 * DH; pv0 += 64; pv1 += 64;
      ka = *(const uint4*)pk0; kb = *(const uint4*)pk1;
      va = *(const uint4*)pv0; vb = *(const uint4*)pv1;
    }

    // S^T = K Q^T : A=K (m=kv), B=Q (n=q). sacc[ni]: kv=16ni+4quad+reg, q=r
    f32x4 sacc[4] = {};
#pragma unroll
    for (int ks = 0; ks < 2; ++ks) {
      const f16x8 bq = ks ? bq1 : bq0;
#pragma unroll
      for (int ni = 0; ni < 4; ++ni) {
        f16x8 ak =
            *(const f16x8*)&Ks[cur][(ni * 16 + r) * LDK + ks * 32 + quad * 8];
        sacc[ni] =
            __builtin_amdgcn_mfma_f32_16x16x32_f16(ak, bq, sacc[ni], 0, 0, 0);
      }
    }

    // mask (diagonal tile only), P = exp2(S'-SHIFT), in-lane l, pack chunks
    if (it == ntiles - 1) {
      const int qloc = wv * 16 + r;  // lane's q within the 64-row block
#pragma unroll
      for (int ni = 0; ni < 4; ++ni)
#pragma unroll
        for (int reg = 0; reg < 4; ++reg)
          if (16 * ni + 4 * quad + reg > qloc) sacc[ni][reg] = -1e30f;
    }
    int P4x[4], P4y[4];
    float lp = 0.f;
#pragma unroll
    for (int ni = 0; ni < 4; ++ni) {
      const float p0 = exp2f(sacc[ni][0] - SHIFT);
      const float p1 = exp2f(sacc[ni][1] - SHIFT);
      const float p2 = exp2f(sacc[ni][2] - SHIFT);
      const float p3 = exp2f(sacc[ni][3] - SHIFT);
      lp += (p0 + p1) + (p2 + p3);
      P4x[ni] = __builtin_bit_cast(int, __builtin_amdgcn_cvt_pkrtz(p0, p1));
      P4y[ni] = __builtin_bit_cast(int, __builtin_amdgcn_cvt_pkrtz(p2, p3));
    }
    lp += __shfl_xor(lp, 16, 64);
    lp += __shfl_xor(lp, 32, 64);
    l_i += lp;

    // O^T += V P^T : A=V-frag from Vs[dh][kv], B=P-frag built via shfl.
    // B(ks) lane(quad,r): kv chunk c=8ks+2quad (lo), c+1 (hi);
    //   source: P4[2ks + (quad>>1)] at lanes sl (lo), sh (hi).
#pragma unroll
    for (int ks = 0; ks < 2; ++ks) {
      const int ax = __shfl(P4x[2 * ks], sl, 64);
      const int ay = __shfl(P4y[2 * ks], sl, 64);
      const int bx = __shfl(P4x[2 * ks + 1], sl, 64);
      const int by = __shfl(P4y[2 * ks + 1], sl, 64);
      const int cx = __shfl(P4x[2 * ks], sh, 64);
      const int cy = __shfl(P4y[2 * ks], sh, 64);
      const int dx = __shfl(P4x[2 * ks + 1], sh, 64);
      const int dy = __shfl(P4y[2 * ks + 1], sh, 64);
      int4 bi;
      bi.x = quad >= 2 ? bx : ax;
      bi.y = quad >= 2 ? by : ay;
      bi.z = quad >= 2 ? dx : cx;
      bi.w = quad >= 2 ? dy : cy;
      const f16x8 bp = __builtin_bit_cast(f16x8, bi);
#pragma unroll
      for (int ni = 0; ni < 4; ++ni) {
        f16x8 av =
            *(const f16x8*)&Vs[cur][(ni * 16 + r) * LDK + ks * 32 + quad * 8];
        oaccT[ni] =
            __builtin_amdgcn_mfma_f32_16x16x32_f16(av, bp, oaccT[ni], 0, 0, 0);
      }
    }
  }

  // epilogue: lane holds q = q0+wv*16+r (same lane as l_i); dh contiguous x4
  const int b = bh >> 4, h = bh & 15;
  const float rl = 1.0f / l_i;
  _Float16* crow =
      ctx + ((size_t)b * Sdim + q0 + wv * 16 + r) * Ddim + h * DH + quad * 4;
#pragma unroll
  for (int ni = 0; ni < 4; ++ni) {
    int2 st;
    st.x = __builtin_bit_cast(
        int, __builtin_amdgcn_cvt_pkrtz(oaccT[ni][0] * rl, oaccT[ni][1] * rl));
    st.y = __builtin_bit_cast(
        int, __builtin_amdgcn_cvt_pkrtz(oaccT[ni][2] * rl, oaccT[ni][3] * rl));
    *(int2*)(crow + ni * 16) = st;
  }
}

// ------------------------------ launcher -----------------------------------
extern "C" void kernel_launch(void* const* d_in, const int* in_sizes, int n_in,
                              void* d_out, int out_size, void* d_ws,
                              size_t ws_size, hipStream_t stream) {
  const float* hid = (const float*)d_in[0];
  const float* Wq = (const float*)d_in[1];
  const float* bq = (const float*)d_in[2];
  const float* Wk = (const float*)d_in[3];
  const float* bk = (const float*)d_in[4];
  const float* Wv = (const float*)d_in[5];
  const float* bv = (const float*)d_in[6];
  const float* Wo = (const float*)d_in[7];
  const float* bo = (const float*)d_in[8];

  char* ws = (char*)d_ws;
  _Float16* Xh = (_Float16*)(ws);                  // 8 MiB (reused as ctx)
  _Float16* Wqt = (_Float16*)(ws + (8ull << 20));  // 2 MiB each
  _Float16* Wkt = (_Float16*)(ws + (10ull << 20));
  _Float16* Wvt = (_Float16*)(ws + (12ull << 20));
  _Float16* Wot = (_Float16*)(ws + (14ull << 20));
  _Float16* Qb = (_Float16*)(ws + (16ull << 20));  // 8 MiB each
  _Float16* Kb = (_Float16*)(ws + (24ull << 20));
  _Float16* Vtb = (_Float16*)(ws + (32ull << 20)); // end: 40 MiB
  _Float16* ctx = Xh;

  WtArgs wa{Wq, Wk, Wv, Wo, Wqt, Wkt, Wvt, Wot};
  prep<<<dim3(2048 + 1024), 256, 0, stream>>>(hid, Xh, wa);

  GemmArgs g1{Xh, Wqt, Wkt, Wvt, bq, bk, bv, Qb, Kb, Vtb};
  gemm128<0><<<dim3(Mrows / 128, Ddim / 128, 3), 256, 0, stream>>>(g1);

  attn<<<dim3(1024), 256, 0, stream>>>(Qb, Kb, Vtb, ctx);

  GemmArgs g2{ctx, Wot, Wot, Wot, bo, bo, bo, d_out, d_out, d_out};
  gemm128<1><<<dim3(Mrows / 128, Ddim / 128, 1), 256, 0, stream>>>(g2);
}

// Round 7
// 209.044 us; speedup vs baseline: 1.0344x; 1.0344x over previous
//
#include <hip/hip_runtime.h>

// ---------------------------------------------------------------------------
// MultiHeadAttention (B=2,S=2048,H=16,DH=64,D=1024), fp32 in/out, fp16 MFMA.
// Pipeline: prep (xcvt + wtrans) -> QKV gemm -> memset(Ob,Lb) -> attn v7
//           -> norml -> O gemm (64x128 tiles).
// attn v7: KV-CHUNKED flash. Fixed-shift softmax makes partials additive:
//   each block does <=8 KV tiles of one (bh,qt) and atomicAdds fp32 partial
//   O + l into workspace. 2560 near-uniform blocks -> real occupancy.
//   S^T = K*Q^T (in-lane softmax, 2 shfl/tile); PV via verified v3
//   wave-private LDS-P path (v4's shfl transform measured slower).
// Workspace overlay: Ob(16MB fp32) sits on Xh+Wq/k/v (dead after QKV gemm);
//   ctx(fp16) sits on Qb (dead after attn). Total 42.25 MB.
// MFMA 16x16x32 f16 layouts (verified rounds 1-6):
//   A: m=lane&15, k=quad*8+j   B: n=lane&15, k=quad*8+j
//   C/D: col(n)=lane&15, row(m)=quad*4+reg
// ---------------------------------------------------------------------------

typedef _Float16 f16x8 __attribute__((ext_vector_type(8)));
typedef float f32x4 __attribute__((ext_vector_type(4)));

#define GLD_LDS16(g, l)                                                        \
  __builtin_amdgcn_global_load_lds(                                            \
      (__attribute__((address_space(1))) const unsigned int*)(g),              \
      (__attribute__((address_space(3))) unsigned int*)(l), 16, 0, 0)

static constexpr int Sdim = 2048;
static constexpr int Ddim = 1024;
static constexpr int NH = 16;
static constexpr int DH = 64;
static constexpr int Mrows = 4096;  // B*S
static constexpr int CT = 8;        // KV tiles per attn chunk

// Q prescale: 1/sqrt(64) * log2(e), so P = exp2(S' - SHIFT) natively.
static constexpr float QSCALE = 0.125f * 1.44269504f;
static constexpr float SHIFT = 4.0f;

// ------------------- prep: X fp32->fp16  +  W [K,N]->fp16 [N,K] ------------
struct WtArgs {
  const float *s0, *s1, *s2, *s3;
  _Float16 *d0, *d1, *d2, *d3;
};

__global__ __launch_bounds__(256) void prep(const float* __restrict__ X,
                                            _Float16* __restrict__ Y, WtArgs a) {
  __shared__ _Float16 L[64 * 72];
  const int bid = blockIdx.x, t = threadIdx.x;
  if (bid < 2048) {  // xcvt: 4096x1024 fp32 -> fp16
    size_t i = ((size_t)bid * 256 + t) * 8;
    float4 f0 = *(const float4*)(X + i);
    float4 f1 = *(const float4*)(X + i + 4);
    alignas(16) _Float16 h[8] = {(_Float16)f0.x, (_Float16)f0.y, (_Float16)f0.z,
                                 (_Float16)f0.w, (_Float16)f1.x, (_Float16)f1.y,
                                 (_Float16)f1.z, (_Float16)f1.w};
    *(uint4*)(Y + i) = *(const uint4*)h;
    return;
  }
  const int w = bid - 2048, z = w >> 8, rem = w & 255;
  const float* src = z == 0 ? a.s0 : z == 1 ? a.s1 : z == 2 ? a.s2 : a.s3;
  _Float16* dst = z == 0 ? a.d0 : z == 1 ? a.d1 : z == 2 ? a.d2 : a.d3;
  const int k0 = (rem & 15) * 64, n0 = (rem >> 4) * 64;
#pragma unroll
  for (int i = 0; i < 4; ++i) {
    int c = i * 256 + t;  // 1024 chunks of 4 floats
    int row = c >> 4, cc = c & 15;
    float4 f = *(const float4*)&src[(size_t)(k0 + row) * Ddim + n0 + cc * 4];
    L[(cc * 4 + 0) * 72 + row] = (_Float16)f.x;
    L[(cc * 4 + 1) * 72 + row] = (_Float16)f.y;
    L[(cc * 4 + 2) * 72 + row] = (_Float16)f.z;
    L[(cc * 4 + 3) * 72 + row] = (_Float16)f.w;
  }
  __syncthreads();
#pragma unroll
  for (int i = 0; i < 2; ++i) {
    int c = i * 256 + t;  // 512 chunks of 8 halves
    int n = c >> 3, cc = c & 7;
    *(uint4*)&dst[(size_t)(n0 + n) * Ddim + k0 + cc * 8] =
        *(const uint4*)&L[n * 72 + cc * 8];
  }
}

// ----------------------- 128x128 GEMM (QKV only) ---------------------------
// A [M,1024] fp16, Bt [N=1024,K=1024] fp16. +bias -> fp16.
// z==0 (Q): prescale QSCALE -> [B,H,S,64]; z==1 (K): -> [B,H,S,64];
// z==2 (V): -> transposed [B,H,64,S].
struct GemmArgs {
  const _Float16* A;
  const _Float16 *Bt0, *Bt1, *Bt2;
  const float *b0, *b1, *b2;
  void *o0, *o1, *o2;
};

__global__ __launch_bounds__(256) void gemmQKV(GemmArgs g) {
  constexpr int K = 1024;
  __shared__ _Float16 As[128 * 32];
  __shared__ _Float16 Bs[128 * 32];
  const int z = blockIdx.z;
  const _Float16* A = g.A;
  const _Float16* Bt = z == 0 ? g.Bt0 : z == 1 ? g.Bt1 : g.Bt2;
  const float* bias = z == 0 ? g.b0 : z == 1 ? g.b1 : g.b2;
  void* out = z == 0 ? g.o0 : z == 1 ? g.o1 : g.o2;
  const int m0 = blockIdx.x * 128, n0 = blockIdx.y * 128;
  const int t = threadIdx.x, lane = t & 63, wv = t >> 6;
  const int wm = wv >> 1, wn = wv & 1, quad = lane >> 4, r = lane & 15;

  const int c0 = wv * 64 + lane, c1 = c0 + 256;
  const _Float16* ga0 = A + (size_t)(m0 + (c0 >> 2)) * K + (c0 & 3) * 8;
  const _Float16* ga1 = A + (size_t)(m0 + (c1 >> 2)) * K + (c1 & 3) * 8;
  const _Float16* gb0 = Bt + (size_t)(n0 + (c0 >> 2)) * K + (c0 & 3) * 8;
  const _Float16* gb1 = Bt + (size_t)(n0 + (c1 >> 2)) * K + (c1 & 3) * 8;
  char* lA0 = (char*)As + (wv * 64) * 16;
  char* lA1 = (char*)As + (256 + wv * 64) * 16;
  char* lB0 = (char*)Bs + (wv * 64) * 16;
  char* lB1 = (char*)Bs + (256 + wv * 64) * 16;

  f32x4 acc[4][4] = {};
  for (int kt = 0; kt < K; kt += 32) {
    GLD_LDS16(ga0 + kt, lA0);
    GLD_LDS16(ga1 + kt, lA1);
    GLD_LDS16(gb0 + kt, lB0);
    GLD_LDS16(gb1 + kt, lB1);
    __syncthreads();
    f16x8 af[4], bf[4];
#pragma unroll
    for (int mi = 0; mi < 4; ++mi)
      af[mi] = *(const f16x8*)&As[(wm * 64 + mi * 16 + r) * 32 + quad * 8];
#pragma unroll
    for (int ni = 0; ni < 4; ++ni)
      bf[ni] = *(const f16x8*)&Bs[(wn * 64 + ni * 16 + r) * 32 + quad * 8];
#pragma unroll
    for (int mi = 0; mi < 4; ++mi)
#pragma unroll
      for (int ni = 0; ni < 4; ++ni)
        acc[mi][ni] = __builtin_amdgcn_mfma_f32_16x16x32_f16(af[mi], bf[ni],
                                                             acc[mi][ni], 0, 0, 0);
    __syncthreads();
  }

  const float scale = (z == 0) ? QSCALE : 1.0f;
  float bv[4];
#pragma unroll
  for (int ni = 0; ni < 4; ++ni) bv[ni] = bias[n0 + wn * 64 + ni * 16 + r];
#pragma unroll
  for (int mi = 0; mi < 4; ++mi) {
#pragma unroll
    for (int ni = 0; ni < 4; ++ni) {
      const int n = n0 + wn * 64 + ni * 16 + r;
      if (z == 2) {
        alignas(8) _Float16 h4[4];
#pragma unroll
        for (int reg = 0; reg < 4; ++reg)
          h4[reg] = (_Float16)(acc[mi][ni][reg] + bv[ni]);
        const int m = m0 + wm * 64 + mi * 16 + quad * 4;
        const int b = m >> 11, s = m & 2047, h = n >> 6, dh = n & 63;
        *(uint2*)&((_Float16*)out)[((size_t)(b * NH + h) * DH + dh) * Sdim + s] =
            *(const uint2*)h4;
      } else {
#pragma unroll
        for (int reg = 0; reg < 4; ++reg) {
          const int m = m0 + wm * 64 + mi * 16 + quad * 4 + reg;
          const float v = (acc[mi][ni][reg] + bv[ni]) * scale;
          const int b = m >> 11, s = m & 2047, h = n >> 6, dh = n & 63;
          ((_Float16*)out)[(((size_t)(b * NH + h) * Sdim + s) << 6) + dh] =
              (_Float16)v;
        }
      }
    }
  }
}

// ------------------------- flash attention v7 ------------------------------
// grid 2560. Block = one KV chunk (<=8 tiles) of one (bh, qt). Partials are
// additive under fixed-shift softmax -> atomicAdd fp32 O + l.
// id -> xcd=id&7, j=id>>3 (0..319): b2=j/80 -> bh=xcd+8*b2 (XCD-pinned);
// jj=j%80 -> (qt, chunk c) via chunk-count table {1,1,..,2,2,..,3,..,4}.
__global__ __launch_bounds__(256) void attn(const _Float16* __restrict__ Q,
                                            const _Float16* __restrict__ Kk,
                                            const _Float16* __restrict__ Vt,
                                            float* __restrict__ Ob,
                                            float* __restrict__ Lb) {
  constexpr int LDK = 72;
  __shared__ _Float16 Ks[64 * LDK], Vs[64 * LDK], Ps[4 * 16 * LDK];
  const int id = blockIdx.x, xcd = id & 7, j = id >> 3;
  const int b2 = j / 80, jj = j - 80 * b2;
  int qt, c;
  if (jj < 8) {
    qt = jj; c = 0;
  } else if (jj < 24) {
    qt = 8 + ((jj - 8) >> 1); c = (jj - 8) & 1;
  } else if (jj < 48) {
    qt = 16 + (jj - 24) / 3; c = (jj - 24) % 3;
  } else {
    qt = 24 + ((jj - 48) >> 2); c = (jj - 48) & 3;
  }
  const int bh = xcd + 8 * b2;
  const int t = threadIdx.x, lane = t & 63, wv = t >> 6;
  const int quad = lane >> 4, r = lane & 15;
  const int q0 = qt * 64;
  const int it0 = c * CT;
  const int itn = (it0 + CT < qt + 1) ? it0 + CT : qt + 1;
  const _Float16* Kg = Kk + (size_t)bh * Sdim * DH;  // [S, 64]
  const _Float16* Vg = Vt + (size_t)bh * DH * Sdim;  // [64, S]
  _Float16* Pw = Ps + wv * 16 * LDK;

  // Q B-frags for the wave's 16 q rows (q = wv*16 + r)
  const _Float16* Qrow = Q + ((size_t)bh * Sdim + q0 + wv * 16 + r) * DH;
  const f16x8 bq0 = *(const f16x8*)(Qrow + quad * 8);
  const f16x8 bq1 = *(const f16x8*)(Qrow + 32 + quad * 8);

  // staging: 512 16B-chunks per 64x64 tile; thread covers rows sr0, sr0+32
  const int sr0 = t >> 3, sr1 = sr0 + 32, sc0 = (t & 7) * 8;
  const _Float16* pk0 = Kg + (size_t)(it0 * 64 + sr0) * DH + sc0;
  const _Float16* pk1 = Kg + (size_t)(it0 * 64 + sr1) * DH + sc0;
  const _Float16* pv0 = Vg + (size_t)sr0 * Sdim + it0 * 64 + sc0;
  const _Float16* pv1 = Vg + (size_t)sr1 * Sdim + it0 * 64 + sc0;

  float l_i = 0.f;
  f32x4 oacc[4] = {};  // q = q0+wv*16+quad*4+reg, dh = ni*16+r

  uint4 ka = *(const uint4*)pk0, kb = *(const uint4*)pk1;
  uint4 va = *(const uint4*)pv0, vb = *(const uint4*)pv1;

  for (int it = it0; it < itn; ++it) {
    __syncthreads();  // prior tile's LDS reads complete
    *(uint4*)&Ks[sr0 * LDK + sc0] = ka;
    *(uint4*)&Ks[sr1 * LDK + sc0] = kb;
    *(uint4*)&Vs[sr0 * LDK + sc0] = va;
    *(uint4*)&Vs[sr1 * LDK + sc0] = vb;
    __syncthreads();
    if (it + 1 < itn) {  // prefetch next tile (overlaps compute)
      pk0 += 64 * DH; pk1 += 64 * DH; pv0 += 64; pv1 += 64;
      ka = *(const uint4*)pk0; kb = *(const uint4*)pk1;
      va = *(const uint4*)pv0; vb = *(const uint4*)pv1;
    }

    // S^T = K Q^T : A=K (m=kv), B=Q (n=q). sacc[ni]: kv=16ni+4quad+reg, q=r
    f32x4 sacc[4] = {};
#pragma unroll
    for (int ks = 0; ks < 2; ++ks) {
      const f16x8 bq = ks ? bq1 : bq0;
#pragma unroll
      for (int ni = 0; ni < 4; ++ni) {
        f16x8 ak = *(const f16x8*)&Ks[(ni * 16 + r) * LDK + ks * 32 + quad * 8];
        sacc[ni] =
            __builtin_amdgcn_mfma_f32_16x16x32_f16(ak, bq, sacc[ni], 0, 0, 0);
      }
    }

    // diagonal mask; P = exp2(S'-SHIFT); in-lane l; LDS-transpose to Pw[q][kv]
    if (it == qt) {
      const int qloc = wv * 16 + r;
#pragma unroll
      for (int ni = 0; ni < 4; ++ni)
#pragma unroll
        for (int reg = 0; reg < 4; ++reg)
          if (16 * ni + 4 * quad + reg > qloc) sacc[ni][reg] = -1e30f;
    }
    float lp = 0.f;
#pragma unroll
    for (int ni = 0; ni < 4; ++ni) {
      const float p0 = exp2f(sacc[ni][0] - SHIFT);
      const float p1 = exp2f(sacc[ni][1] - SHIFT);
      const float p2 = exp2f(sacc[ni][2] - SHIFT);
      const float p3 = exp2f(sacc[ni][3] - SHIFT);
      lp += (p0 + p1) + (p2 + p3);
      int2 st;
      st.x = __builtin_bit_cast(int, __builtin_amdgcn_cvt_pkrtz(p0, p1));
      st.y = __builtin_bit_cast(int, __builtin_amdgcn_cvt_pkrtz(p2, p3));
      *(int2*)&Pw[r * LDK + ni * 16 + quad * 4] = st;  // ds_write_b64
    }
    lp += __shfl_xor(lp, 16, 64);
    lp += __shfl_xor(lp, 32, 64);
    l_i += lp;  // lane's q = wv*16 + r (all 4 quads hold the same sum)

    // O += P V : A = Pw rows (m=q, wave-private, no barrier), B = Vs (n=dh)
#pragma unroll
    for (int ks = 0; ks < 2; ++ks) {
      f16x8 ap = *(const f16x8*)&Pw[r * LDK + ks * 32 + quad * 8];
#pragma unroll
      for (int ni = 0; ni < 4; ++ni) {
        f16x8 av = *(const f16x8*)&Vs[(ni * 16 + r) * LDK + ks * 32 + quad * 8];
        oacc[ni] =
            __builtin_amdgcn_mfma_f32_16x16x32_f16(ap, av, oacc[ni], 0, 0, 0);
      }
    }
  }

  // epilogue: atomicAdd partials
  const int b = bh >> 4, h = bh & 15;
  if (quad == 0)  // one lane per q (quads hold duplicates)
    atomicAdd(&Lb[(size_t)bh * Sdim + q0 + wv * 16 + r], l_i);
  float* obase = Ob + ((size_t)b * Sdim + q0 + wv * 16) * Ddim + h * DH;
#pragma unroll
  for (int reg = 0; reg < 4; ++reg)
#pragma unroll
    for (int ni = 0; ni < 4; ++ni)
      atomicAdd(obase + (size_t)(quad * 4 + reg) * Ddim + ni * 16 + r,
                oacc[ni][reg]);
}

// ---------------- normalize: ctx fp16 = Ob fp32 / l ------------------------
__global__ __launch_bounds__(256) void norml(const float* __restrict__ Ob,
                                             const float* __restrict__ Lb,
                                             _Float16* __restrict__ ctx) {
  size_t i = ((size_t)blockIdx.x * 256 + threadIdx.x) * 8;
  const int m = (int)(i >> 10), n = (int)(i & 1023);
  const float rl = 1.0f / Lb[(size_t)(((m >> 11) << 4) + (n >> 6)) * Sdim + (m & 2047)];
  float4 f0 = *(const float4*)(Ob + i);
  float4 f1 = *(const float4*)(Ob + i + 4);
  alignas(16) _Float16 hh[8] = {
      (_Float16)(f0.x * rl), (_Float16)(f0.y * rl), (_Float16)(f0.z * rl),
      (_Float16)(f0.w * rl), (_Float16)(f1.x * rl), (_Float16)(f1.y * rl),
      (_Float16)(f1.z * rl), (_Float16)(f1.w * rl)};
  *(uint4*)(ctx + i) = *(const uint4*)hh;
}

// ---------------- O-proj GEMM: 64x128 tiles, grid 512 ----------------------
__global__ __launch_bounds__(256) void gemmO(const _Float16* __restrict__ A,
                                             const _Float16* __restrict__ Bt,
                                             const float* __restrict__ bias,
                                             float* __restrict__ out) {
  constexpr int K = 1024;
  __shared__ _Float16 As[64 * 32];
  __shared__ _Float16 Bs[128 * 32];
  const int m0 = blockIdx.x * 64, n0 = blockIdx.y * 128;
  const int t = threadIdx.x, lane = t & 63, wv = t >> 6;
  const int quad = lane >> 4, r = lane & 15;

  const _Float16* ga = A + (size_t)(m0 + (t >> 2)) * K + (t & 3) * 8;
  const int c1 = t + 256;
  const _Float16* gb0 = Bt + (size_t)(n0 + (t >> 2)) * K + (t & 3) * 8;
  const _Float16* gb1 = Bt + (size_t)(n0 + (c1 >> 2)) * K + (c1 & 3) * 8;
  char* lA = (char*)As + t * 16;
  char* lB0 = (char*)Bs + t * 16;
  char* lB1 = (char*)Bs + (256 + t) * 16;

  f32x4 acc[4][2] = {};
  for (int kt = 0; kt < K; kt += 32) {
    GLD_LDS16(ga + kt, lA);
    GLD_LDS16(gb0 + kt, lB0);
    GLD_LDS16(gb1 + kt, lB1);
    __syncthreads();
    f16x8 af[4], bf[2];
#pragma unroll
    for (int mi = 0; mi < 4; ++mi)
      af[mi] = *(const f16x8*)&As[(mi * 16 + r) * 32 + quad * 8];
#pragma unroll
    for (int ni = 0; ni < 2; ++ni)
      bf[ni] = *(const f16x8*)&Bs[(wv * 32 + ni * 16 + r) * 32 + quad * 8];
#pragma unroll
    for (int mi = 0; mi < 4; ++mi)
#pragma unroll
      for (int ni = 0; ni < 2; ++ni)
        acc[mi][ni] = __builtin_amdgcn_mfma_f32_16x16x32_f16(af[mi], bf[ni],
                                                             acc[mi][ni], 0, 0, 0);
    __syncthreads();
  }

  const float bv0 = bias[n0 + wv * 32 + r];
  const float bv1 = bias[n0 + wv * 32 + 16 + r];
#pragma unroll
  for (int mi = 0; mi < 4; ++mi)
#pragma unroll
    for (int reg = 0; reg < 4; ++reg) {
      const int m = m0 + mi * 16 + quad * 4 + reg;
      float* orow = out + (size_t)m * Ddim + n0 + wv * 32 + r;
      orow[0] = acc[mi][0][reg] + bv0;
      orow[16] = acc[mi][1][reg] + bv1;
    }
}

// ------------------------------ launcher -----------------------------------
extern "C" void kernel_launch(void* const* d_in, const int* in_sizes, int n_in,
                              void* d_out, int out_size, void* d_ws,
                              size_t ws_size, hipStream_t stream) {
  const float* hid = (const float*)d_in[0];
  const float* Wq = (const float*)d_in[1];
  const float* bq = (const float*)d_in[2];
  const float* Wk = (const float*)d_in[3];
  const float* bk = (const float*)d_in[4];
  const float* Wv = (const float*)d_in[5];
  const float* bv = (const float*)d_in[6];
  const float* Wo = (const float*)d_in[7];
  const float* bo = (const float*)d_in[8];

  char* ws = (char*)d_ws;
  // Overlay plan (stream-ordered lifetimes):
  //  [0,8)   Xh (fp16 X)          — dead after QKV gemm
  //  [8,14)  Wqt/Wkt/Wvt (2 each) — dead after QKV gemm
  //  [0,16)  Ob (fp32 O-accum)    — lives attn..norml   (overlays the above)
  //  [16,24) Qb                   — dead after attn; then ctx (fp16)
  //  [24,32) Kb ; [32,40) Vtb ; [40,42) Wot ; [42,42.25) Lb
  _Float16* Xh = (_Float16*)(ws);
  _Float16* Wqt = (_Float16*)(ws + (8ull << 20));
  _Float16* Wkt = (_Float16*)(ws + (10ull << 20));
  _Float16* Wvt = (_Float16*)(ws + (12ull << 20));
  float* Ob = (float*)(ws);
  _Float16* Qb = (_Float16*)(ws + (16ull << 20));
  _Float16* ctx = (_Float16*)(ws + (16ull << 20));
  _Float16* Kb = (_Float16*)(ws + (24ull << 20));
  _Float16* Vtb = (_Float16*)(ws + (32ull << 20));
  _Float16* Wot = (_Float16*)(ws + (40ull << 20));
  float* Lb = (float*)(ws + (42ull << 20));

  WtArgs wa{Wq, Wk, Wv, Wo, Wqt, Wkt, Wvt, Wot};
  prep<<<dim3(2048 + 1024), 256, 0, stream>>>(hid, Xh, wa);

  GemmArgs g1{Xh, Wqt, Wkt, Wvt, bq, bk, bv, Qb, Kb, Vtb};
  gemmQKV<<<dim3(Mrows / 128, Ddim / 128, 3), 256, 0, stream>>>(g1);

  // zero the accumulators (Xh/Wq..Wv are dead now; capture-legal async memset)
  hipMemsetAsync(Ob, 0, 16ull << 20, stream);
  hipMemsetAsync(Lb, 0, (size_t)32 * Sdim * sizeof(float), stream);

  attn<<<dim3(2560), 256, 0, stream>>>(Qb, Kb, Vtb, Ob, Lb);

  norml<<<dim3(2048), 256, 0, stream>>>(Ob, Lb, ctx);

  gemmO<<<dim3(Mrows / 64, Ddim / 128), 256, 0, stream>>>(ctx, Wot, bo,
                                                          (float*)d_out);
}